// Round 11
// baseline (1143.540 us; speedup 1.0000x reference)
//
#include <hip/hip_runtime.h>
#include <hip/hip_fp16.h>

#define TS 40
#define NB 2048
#define NU 1024
#define NI 1024
#define ND 2048
#define UD (1024 * 2048)  // elems in one W_t (4 MB as f16)

typedef _Float16 half8 __attribute__((ext_vector_type(8)));
typedef _Float16 half4v __attribute__((ext_vector_type(4)));
typedef float floatx4 __attribute__((ext_vector_type(4)));

__device__ __forceinline__ float tanh_fast(float v) {
  float e = __expf(2.0f * v);
  return 1.0f - 2.0f / (e + 1.0f);  // inf-safe
}

__device__ __forceinline__ void gload16(const void* g, void* l) {
  __builtin_amdgcn_global_load_lds(
      (const __attribute__((address_space(1))) void*)g,
      (__attribute__((address_space(3))) void*)l, 16, 0, 0);
}

// ===== fragment-major tile layout (verified R6-R10) =========================
// tile = 64x64 f16 = 8192 B as 512 x 16B chunks.
// chunk(r,c8) = ((r>>4)*2 + (c8>>2))*64 + (c8&3)*16 + (r&15)
__device__ __forceinline__ int tile_off(int r, int c8) {
  return (((((r >> 4) * 2 + (c8 >> 2)) << 6) + ((c8 & 3) << 4) + (r & 15)) << 4);
}

// W_tiled:  [t][ut 0..15][kt 0..31][8192B]  (kt<16: h-part, kt>=16: x-part)
// X_tiled:  [t][bt 0..31][kt 0..15][8192B]
// h_tiled:  [slot][bt 0..31][ut 0..15][8192B]
// pre_tiled:[slot][bt 0..31][ut 0..15][8192B]

// ---------------- wprep: Qw (fp32) -> W tiled f16 (verified) ----------------
__global__ __launch_bounds__(256) void wprep(
    const float* __restrict__ Qw, const float* __restrict__ Bt,
    _Float16* __restrict__ W)
{
  __shared__ _Float16 ldsQ[64 * 512];
  __shared__ float ldsB[TS * 8];
  const int tid = threadIdx.x;
  const int kt = blockIdx.x;   // 0..31
  const int ut = blockIdx.y;   // 0..15
  for (int i = tid; i < TS * 8; i += 256) ldsB[i] = Bt[i];
  const float* qb = Qw + (size_t)(kt * 64) * 8192 + ut * 512;
#pragma unroll
  for (int i = 0; i < 32; ++i) {
    int s = i * 256 + tid;
    int dk = s >> 7, c4 = s & 127;
    float4 v = *(const float4*)(qb + (size_t)dk * 8192 + c4 * 4);
    _Float16* d = &ldsQ[dk * 512 + c4 * 4];
    d[0] = (_Float16)v.x; d[1] = (_Float16)v.y;
    d[2] = (_Float16)v.z; d[3] = (_Float16)v.w;
  }
  __syncthreads();
  const int w = tid >> 6, lane = tid & 63;
  const int dur = lane & 7, ko = lane >> 3;
#pragma unroll 1
  for (int sp = 0; sp < 2; ++sp) {
    const int stripe = w * 2 + sp;
    const int du = stripe * 8 + dur;
    float Q[8][8];
#pragma unroll
    for (int j = 0; j < 8; ++j)
#pragma unroll
      for (int q = 0; q < 8; ++q)
        Q[j][q] = (float)ldsQ[(ko * 8 + j) * 512 + du * 8 + q];
    const int obase = tile_off(du, ko);
#pragma unroll 1
    for (int t = 0; t < TS; ++t) {
      float b[8];
#pragma unroll
      for (int q = 0; q < 8; ++q) b[q] = ldsB[t * 8 + q];
      half8 v;
#pragma unroll
      for (int j = 0; j < 8; ++j) {
        float s = 0.f;
#pragma unroll
        for (int q = 0; q < 8; ++q) s += Q[j][q] * b[q];
        v[j] = (_Float16)s;
      }
      size_t tile = ((size_t)t * 16 + ut) * 32 + kt;
      *(half8*)((char*)W + tile * 8192 + obase) = v;
    }
  }
}

// ---------------- xprep: x fp32 -> X tiled f16 (verified) -------------------
__global__ __launch_bounds__(256) void xprep(
    const float* __restrict__ x, _Float16* __restrict__ X)
{
  __shared__ char stage[8192];
  const int tid = threadIdx.x;
  const int bt = blockIdx.x, t = blockIdx.y;
  char* outb = (char*)X + ((size_t)(t * 32 + bt) * 16) * 8192;
  const int r = tid >> 2, cq = tid & 3;
#pragma unroll 1
  for (int kt = 0; kt < 16; ++kt) {
    const float* src =
        x + (size_t)(bt * 64 + r) * (TS * NI) + (size_t)t * NI + kt * 64 + cq * 16;
    float4 a0 = *(const float4*)(src);
    float4 a1 = *(const float4*)(src + 4);
    float4 a2 = *(const float4*)(src + 8);
    float4 a3 = *(const float4*)(src + 12);
    half8 h0, h1;
    h0[0] = (_Float16)a0.x; h0[1] = (_Float16)a0.y;
    h0[2] = (_Float16)a0.z; h0[3] = (_Float16)a0.w;
    h0[4] = (_Float16)a1.x; h0[5] = (_Float16)a1.y;
    h0[6] = (_Float16)a1.z; h0[7] = (_Float16)a1.w;
    h1[0] = (_Float16)a2.x; h1[1] = (_Float16)a2.y;
    h1[2] = (_Float16)a2.z; h1[3] = (_Float16)a2.w;
    h1[4] = (_Float16)a3.x; h1[5] = (_Float16)a3.y;
    h1[6] = (_Float16)a3.z; h1[7] = (_Float16)a3.w;
    *(half8*)(stage + tile_off(r, cq * 2)) = h0;
    *(half8*)(stage + tile_off(r, cq * 2 + 1)) = h1;
    __syncthreads();
    uint4 v0 = *(const uint4*)(stage + tid * 32);
    uint4 v1 = *(const uint4*)(stage + tid * 32 + 16);
    *(uint4*)(outb + (size_t)kt * 8192 + tid * 32) = v0;
    *(uint4*)(outb + (size_t)kt * 8192 + tid * 32 + 16) = v1;
    __syncthreads();
  }
}

// ---------------- hinit (verified) ------------------------------------------
__global__ __launch_bounds__(256) void hinit(const float* __restrict__ h0,
                                             _Float16* __restrict__ hb) {
  int g = blockIdx.x * 256 + threadIdx.x;
  int tile_id = g >> 9, rc = g & 511;
  int bt = tile_id >> 4, kt = tile_id & 15;
  int r = rc >> 3, c8 = rc & 7;
  const float* src = h0 + (size_t)(bt * 64 + r) * NU + kt * 64 + c8 * 8;
  float4 v0 = *(const float4*)src;
  float4 v1 = *(const float4*)(src + 4);
  half8 h;
  h[0] = (_Float16)v0.x; h[1] = (_Float16)v0.y;
  h[2] = (_Float16)v0.z; h[3] = (_Float16)v0.w;
  h[4] = (_Float16)v1.x; h[5] = (_Float16)v1.y;
  h[6] = (_Float16)v1.z; h[7] = (_Float16)v1.w;
  *(half8*)((char*)hb + (size_t)tile_id * 8192 + tile_off(r, c8)) = h;
}

// ---------------- fused step ------------------------------------------------
// DOH: h_t = tanh(h_{t-1} @ Wh_t + pre_t)   -> out + h_tiled (both LDS-staged)
// DOX: pre_{t+1} = x_{t+1} @ Wx_{t+1} + b   -> pre_tiled
// Sequential within a block; overlap happens ACROSS the 2 resident blocks/CU.
// 512 blocks, block (bt,ut) owns 64x64. Ring-4 DMA, counted vmcnt.
template <bool DOH, bool DOX>
__global__ __launch_bounds__(256) void fused(
    const _Float16* __restrict__ Wh, const _Float16* __restrict__ preR,
    const _Float16* __restrict__ hprev, _Float16* __restrict__ hnext,
    float* __restrict__ outt,
    const _Float16* __restrict__ Xn, const _Float16* __restrict__ Wn,
    _Float16* __restrict__ preW, const float* __restrict__ bias)
{
  __shared__ char lds[73728];  // 64KB ring-4 + 8KB annex
  const int tid = threadIdx.x, bid = blockIdx.x;
  const int bt = bid & 31, ut = bid >> 5;
  const int lane = tid & 63, w = tid >> 6;
  const int wm = w >> 1, wn = w & 1;
  const int l15 = lane & 15, lk = lane >> 4;
  const int b0 = bt * 64, u0 = ut * 64;

#define GEMM16(Ab, Bb, acc)                                                    \
  {                                                                            \
    auto issue = [&](int kt) {                                                 \
      char* la = lds + (kt & 3) * 16384 + w * 2048;                            \
      const char* ga = (Ab) + (size_t)kt * 8192 + w * 2048 + lane * 16;        \
      const char* gb = (Bb) + (size_t)kt * 8192 + w * 2048 + lane * 16;        \
      gload16(ga, la); gload16(ga + 1024, la + 1024);                          \
      gload16(gb, la + 8192); gload16(gb + 1024, la + 8192 + 1024);            \
    };                                                                         \
    issue(0); issue(1); issue(2);                                              \
    _Pragma("unroll 1")                                                        \
    for (int p = 0; p < 16; ++p) {                                             \
      if (p < 14)       asm volatile("s_waitcnt vmcnt(8)" ::: "memory");       \
      else if (p == 14) asm volatile("s_waitcnt vmcnt(4)" ::: "memory");       \
      else              asm volatile("s_waitcnt vmcnt(0)" ::: "memory");       \
      __builtin_amdgcn_s_barrier();                                            \
      if (p + 3 < 16) issue(p + 3);                                            \
      const char* pA = lds + (p & 3) * 16384;                                  \
      const char* pB = pA + 8192;                                              \
      __builtin_amdgcn_s_setprio(1);                                           \
      _Pragma("unroll")                                                        \
      for (int kk = 0; kk < 2; ++kk) {                                         \
        half8 af[2], bf[2];                                                    \
        _Pragma("unroll")                                                      \
        for (int mf = 0; mf < 2; ++mf)                                         \
          af[mf] = *(const half8*)(pA + ((((wm * 2 + mf) * 2 + kk) << 10) +    \
                                         lane * 16));                          \
        _Pragma("unroll")                                                      \
        for (int nf = 0; nf < 2; ++nf)                                         \
          bf[nf] = *(const half8*)(pB + ((((wn * 2 + nf) * 2 + kk) << 10) +    \
                                         lane * 16));                          \
        _Pragma("unroll")                                                      \
        for (int mf = 0; mf < 2; ++mf)                                         \
          _Pragma("unroll")                                                    \
          for (int nf = 0; nf < 2; ++nf)                                       \
            acc[mf][nf] = __builtin_amdgcn_mfma_f32_16x16x32_f16(              \
                af[mf], bf[nf], acc[mf][nf], 0, 0, 0);                         \
      }                                                                        \
      __builtin_amdgcn_s_setprio(0);                                           \
    }                                                                          \
  }

  if constexpr (DOH) {
    // pre-tile annex load FIRST (oldest vmcnt entries; drained by 1st wait)
    {
      const char* src = (const char*)preR + ((size_t)(bt * 16 + ut)) * 8192 +
                        w * 2048 + lane * 16;
      char* dst = lds + 65536 + w * 2048;
      gload16(src, dst);
      gload16(src + 1024, dst + 1024);
    }
    const char* Hb = (const char*)hprev + (size_t)bt * 16 * 8192;
    const char* Wb = (const char*)Wh + (size_t)ut * 32 * 8192;
    floatx4 acc[2][2] = {};
    GEMM16(Hb, Wb, acc)

    __syncthreads();  // full drain; ring free for staging
    const char* pl = lds + 65536;
#pragma unroll
    for (int mf = 0; mf < 2; ++mf)
#pragma unroll
      for (int nf = 0; nf < 2; ++nf)
#pragma unroll
        for (int j = 0; j < 4; ++j) {
          int bl = wm * 32 + mf * 16 + (lk << 2) + j;
          int ul = wn * 32 + nf * 16 + l15;
          float pv = (float)*(const _Float16*)(pl + tile_off(bl, ul >> 3) +
                                               (ul & 7) * 2);
          float v = tanh_fast(acc[mf][nf][j] + pv);
          *(float*)(lds + bl * 272 + ul * 4) = v;               // out stage
          *(_Float16*)(lds + 32768 + tile_off(bl, ul >> 3) +
                       (ul & 7) * 2) = (_Float16)v;             // h stage
        }
    __syncthreads();  // lgkmcnt drained -> stages visible
    {
      int r = tid >> 2, q = tid & 3;
      const char* so = lds + r * 272 + q * 64;
      float* go = outt + (size_t)(b0 + r) * (TS * NU) + u0 + q * 16;
#pragma unroll
      for (int i = 0; i < 4; ++i)
        *(uint4*)(go + i * 4) = *(const uint4*)(so + i * 16);
      char* gh = (char*)hnext + ((size_t)(bt * 16 + ut)) * 8192;
      *(uint4*)(gh + (size_t)tid * 32) = *(const uint4*)(lds + 32768 + tid * 32);
      *(uint4*)(gh + (size_t)tid * 32 + 16) =
          *(const uint4*)(lds + 32768 + tid * 32 + 16);
    }
  }

  if constexpr (DOX) {
    if constexpr (DOH) __syncthreads();  // protect ring vs epilogue LDS reads
    const char* Xb = (const char*)Xn + (size_t)bt * 16 * 8192;
    const char* WxB = (const char*)Wn + ((size_t)ut * 32 + 16) * 8192;
    floatx4 acc[2][2] = {};
    GEMM16(Xb, WxB, acc)

    __syncthreads();
    float bv0 = bias[u0 + wn * 32 + l15];
    float bv1 = bias[u0 + wn * 32 + 16 + l15];
#pragma unroll
    for (int mf = 0; mf < 2; ++mf)
#pragma unroll
      for (int nf = 0; nf < 2; ++nf)
#pragma unroll
        for (int j = 0; j < 4; ++j) {
          int bl = wm * 32 + mf * 16 + (lk << 2) + j;
          int ul = wn * 32 + nf * 16 + l15;
          float v = acc[mf][nf][j] + (nf ? bv1 : bv0);
          *(_Float16*)(lds + tile_off(bl, ul >> 3) + (ul & 7) * 2) = (_Float16)v;
        }
    __syncthreads();
    {
      char* gp = (char*)preW + ((size_t)(bt * 16 + ut)) * 8192;
      *(uint4*)(gp + (size_t)tid * 32) = *(const uint4*)(lds + tid * 32);
      *(uint4*)(gp + (size_t)tid * 32 + 16) =
          *(const uint4*)(lds + tid * 32 + 16);
    }
  }
#undef GEMM16
}

// ================= round-1 fallback path (small ws) =========================
__global__ __launch_bounds__(256) void wprep_lin(
    const float* __restrict__ Qw, const float* __restrict__ Bt,
    _Float16* __restrict__ W, int t0, int nt)
{
  __shared__ float ldsQ[32 * 257];
  __shared__ float ldsB[TS * 8];
  const int tid = threadIdx.x;
  const int k0 = blockIdx.x * 32;
  const int u0 = blockIdx.y * 32;
  for (int i = tid; i < TS * 8; i += 256) ldsB[i] = Bt[i];
  const float* qbase = Qw + (size_t)k0 * 8192 + (size_t)u0 * 8;
#pragma unroll
  for (int i = 0; i < 8; ++i) {
    int s = i * 256 + tid;
    int r = s >> 6, c4 = s & 63;
    float4 v = *(const float4*)(qbase + (size_t)r * 8192 + c4 * 4);
    float* d = &ldsQ[r * 257 + c4 * 4];
    d[0] = v.x; d[1] = v.y; d[2] = v.z; d[3] = v.w;
  }
  __syncthreads();
  const int kl = tid & 31;
  const int ug = tid >> 5;
#pragma unroll
  for (int p = 0; p < 4; ++p) {
    int uu = p * 8 + ug;
    float q[8];
#pragma unroll
    for (int j = 0; j < 8; ++j) q[j] = ldsQ[kl * 257 + uu * 8 + j];
    size_t obase = (size_t)(u0 + uu) * 2048 + k0 + kl;
    for (int tt = 0; tt < nt; ++tt) {
      const float* bt = &ldsB[(t0 + tt) * 8];
      float v = 0.f;
#pragma unroll
      for (int j = 0; j < 8; ++j) v += q[j] * bt[j];
      W[(size_t)tt * UD + obase] = (_Float16)v;
    }
  }
}

__global__ __launch_bounds__(256) void step_gemm(
    const float* __restrict__ xt, const float* __restrict__ hp, long hstride,
    const _Float16* __restrict__ Wt, const float* __restrict__ bias,
    float* __restrict__ outt)
{
  __shared__ _Float16 ldsA[2][64 * 64];
  __shared__ _Float16 ldsB[2][128 * 64];
  const int tid = threadIdx.x;
  const int b0 = blockIdx.x * 64;
  const int u0 = blockIdx.y * 128;
  const int lane = tid & 63;
  const int wv = tid >> 6;
  const int wm = wv >> 1, wn = wv & 1;
  const int l15 = lane & 15, lk = lane >> 4;

  float4 areg[4];
  uint4 breg[4];

  auto stage_load = [&](int kt) {
    const int k0 = kt * 64;
    const float* src; size_t stride; int koff;
    if (k0 < NU) { src = hp; stride = (size_t)hstride; koff = k0; }
    else { src = xt; stride = (size_t)TS * NI; koff = k0 - NU; }
#pragma unroll
    for (int i = 0; i < 4; ++i) {
      int s = i * 256 + tid;
      int r = s >> 4, c4 = s & 15;
      areg[i] = *(const float4*)(src + (size_t)(b0 + r) * stride + koff + c4 * 4);
    }
    const _Float16* wsrc = Wt + (size_t)u0 * 2048 + k0;
#pragma unroll
    for (int i = 0; i < 4; ++i) {
      int s = i * 256 + tid;
      int u = s >> 3, c8 = s & 7;
      breg[i] = *(const uint4*)(wsrc + (size_t)u * 2048 + c8 * 8);
    }
  };

  auto stage_write = [&](int buf) {
    char* pA = (char*)&ldsA[buf][0];
    char* pB = (char*)&ldsB[buf][0];
#pragma unroll
    for (int i = 0; i < 4; ++i) {
      int s = i * 256 + tid;
      int r = s >> 4, c4 = s & 15;
      half4v h;
      h[0] = (_Float16)areg[i].x; h[1] = (_Float16)areg[i].y;
      h[2] = (_Float16)areg[i].z; h[3] = (_Float16)areg[i].w;
      int off = (r * 128 + c4 * 8) ^ ((r & 7) << 4);
      *(half4v*)(pA + off) = h;
    }
#pragma unroll
    for (int i = 0; i < 4; ++i) {
      int s = i * 256 + tid;
      int u = s >> 3, c8 = s & 7;
      int off = (u * 128 + c8 * 16) ^ ((u & 7) << 4);
      *(uint4*)(pB + off) = breg[i];
    }
  };

  floatx4 acc[2][4] = {};

  auto compute = [&](int buf) {
    const char* pA = (const char*)&ldsA[buf][0];
    const char* pB = (const char*)&ldsB[buf][0];
#pragma unroll
    for (int kk = 0; kk < 2; ++kk) {
      half8 af[2], bf[4];
#pragma unroll
      for (int mf = 0; mf < 2; ++mf) {
        int r = wm * 32 + mf * 16 + l15;
        int off = r * 128 + ((((kk << 2) | lk) ^ (r & 7)) << 4);
        af[mf] = *(const half8*)(pA + off);
      }
#pragma unroll
      for (int nf = 0; nf < 4; ++nf) {
        int u = wn * 64 + nf * 16 + l15;
        int off = u * 128 + ((((kk << 2) | lk) ^ (u & 7)) << 4);
        bf[nf] = *(const half8*)(pB + off);
      }
#pragma unroll
      for (int mf = 0; mf < 2; ++mf)
#pragma unroll
        for (int nf = 0; nf < 4; ++nf)
          acc[mf][nf] =
              __builtin_amdgcn_mfma_f32_16x16x32_f16(af[mf], bf[nf], acc[mf][nf], 0, 0, 0);
    }
  };

  stage_load(0);
  stage_write(0);
  __syncthreads();
#pragma unroll 1
  for (int kt = 0; kt < 32; ++kt) {
    int cur = kt & 1;
    if (kt + 1 < 32) stage_load(kt + 1);
    compute(cur);
    if (kt + 1 < 32) stage_write(cur ^ 1);
    __syncthreads();
  }

#pragma unroll
  for (int mf = 0; mf < 2; ++mf)
#pragma unroll
    for (int nf = 0; nf < 4; ++nf) {
      int u = u0 + wn * 64 + nf * 16 + l15;
      float bv = bias[u];
      int brow = b0 + wm * 32 + mf * 16 + (lk << 2);
#pragma unroll
      for (int j = 0; j < 4; ++j) {
        float prev = acc[mf][nf][j] + bv;
        outt[(size_t)(brow + j) * (TS * NU) + u] = tanh_fast(prev);
      }
    }
}

extern "C" void kernel_launch(void* const* d_in, const int* in_sizes, int n_in,
                              void* d_out, int out_size, void* d_ws, size_t ws_size,
                              hipStream_t stream) {
  const float* x    = (const float*)d_in[0];
  const float* h0   = (const float*)d_in[1];
  const float* Qw   = (const float*)d_in[2];
  const float* bias = (const float*)d_in[3];
  const float* Bt   = (const float*)d_in[4];
  float* out = (float*)d_out;

  char* ws = (char*)d_ws;
  const size_t w_bytes    = (size_t)UD * TS * sizeof(_Float16);      // 167.8 MB
  const size_t x_bytes    = w_bytes;                                 // 167.8 MB
  const size_t slot_bytes = (size_t)NB * NU * sizeof(_Float16);      // 4 MB
  const size_t need = w_bytes + x_bytes + 4 * slot_bytes;            // ~352 MB

  if (ws_size >= need) {
    _Float16* W    = (_Float16*)ws;
    _Float16* X    = (_Float16*)(ws + w_bytes);
    _Float16* preb = (_Float16*)(ws + w_bytes + x_bytes);
    _Float16* hb   = (_Float16*)(ws + w_bytes + x_bytes + 2 * slot_bytes);
    const size_t SLOT = (size_t)NB * NU;  // elems (4 MB)

    wprep<<<dim3(32, 16), 256, 0, stream>>>(Qw, Bt, W);
    xprep<<<dim3(32, 40), 256, 0, stream>>>(x, X);
    hinit<<<dim3(1024), 256, 0, stream>>>(h0, hb);  // slot 0

    // bootstrap: pre_0 into slot 0
    fused<false, true><<<dim3(512), 256, 0, stream>>>(
        W, preb, hb, hb, out, X, W, preb, bias);

    for (int t = 0; t < TS; ++t) {
      const _Float16* Wh = W + (size_t)t * UD;
      const _Float16* preR = preb + (size_t)(t & 1) * SLOT;
      _Float16* preW = preb + (size_t)((t + 1) & 1) * SLOT;
      const _Float16* hprev = hb + (size_t)(t & 1) * SLOT;
      _Float16* hnext = hb + (size_t)((t + 1) & 1) * SLOT;
      float* outt = out + (size_t)t * NU;
      if (t + 1 < TS) {
        const _Float16* Xn = (const _Float16*)((char*)X +
            ((size_t)(t + 1) * 32 * 16) * 8192);
        const _Float16* Wn = W + (size_t)(t + 1) * UD;
        fused<true, true><<<dim3(512), 256, 0, stream>>>(
            Wh, preR, hprev, hnext, outt, Xn, Wn, preW, bias);
      } else {
        fused<true, false><<<dim3(512), 256, 0, stream>>>(
            Wh, preR, hprev, hnext, outt, X, W, preW, bias);
      }
    }
  } else {
    // round-1 fallback (linear W layout)
    _Float16* W = (_Float16*)ws;
    const bool big = ws_size >= w_bytes;
    if (big) wprep_lin<<<dim3(64, 32), 256, 0, stream>>>(Qw, Bt, W, 0, TS);
    for (int t = 0; t < TS; ++t) {
      const _Float16* Wtp;
      if (big) {
        Wtp = W + (size_t)t * UD;
      } else {
        wprep_lin<<<dim3(64, 32), 256, 0, stream>>>(Qw, Bt, W, t, 1);
        Wtp = W;
      }
      const float* hp = (t == 0) ? h0 : out + (size_t)(t - 1) * NU;
      long hstride = (t == 0) ? NU : (long)TS * NU;
      step_gemm<<<dim3(32, 8), 256, 0, stream>>>(
          x + (size_t)t * NI, hp, hstride, Wtp, bias, out + (size_t)t * NU);
    }
  }
}

// Round 12
// 968.950 us; speedup vs baseline: 1.1802x; 1.1802x over previous
//
#include <hip/hip_runtime.h>
#include <hip/hip_fp16.h>

#define TS 40
#define NB 2048
#define NU 1024
#define NI 1024
#define ND 2048
#define UD (1024 * 2048)  // elems in one W_t (4 MB as f16)

typedef _Float16 half8 __attribute__((ext_vector_type(8)));
typedef _Float16 half4v __attribute__((ext_vector_type(4)));
typedef float floatx4 __attribute__((ext_vector_type(4)));

__device__ __forceinline__ float tanh_fast(float v) {
  float e = __expf(2.0f * v);
  return 1.0f - 2.0f / (e + 1.0f);  // inf-safe
}

__device__ __forceinline__ void gload16(const void* g, void* l) {
  __builtin_amdgcn_global_load_lds(
      (const __attribute__((address_space(1))) void*)g,
      (__attribute__((address_space(3))) void*)l, 16, 0, 0);
}

// ===== fragment-major tile layout (verified R6-R10) =========================
// tile = 64x64 f16 = 8192 B as 512 x 16B chunks.
// chunk(r,c8) = ((r>>4)*2 + (c8>>2))*64 + (c8&3)*16 + (r&15)
__device__ __forceinline__ int tile_off(int r, int c8) {
  return (((((r >> 4) * 2 + (c8 >> 2)) << 6) + ((c8 & 3) << 4) + (r & 15)) << 4);
}

// W_tiled:  [t][ut 0..15][kt 0..31][8192B]  (kt<16: h-part, kt>=16: x-part)
// X_tiled:  [t][bt 0..31][kt 0..15][8192B]
// h_tiled:  [slot][bt 0..31][ut 0..15][8192B]
// pre_frag: [t][bid_s = bt+32*ut][tid_s 0..255][16 f16]  (4 MB per t)
//           idx within 16: (mf*2+nf)*4+j for serial frag (mf,nf,j)

// ---------------- wprep: Qw (fp32) -> W tiled f16 (verified) ----------------
__global__ __launch_bounds__(256) void wprep(
    const float* __restrict__ Qw, const float* __restrict__ Bt,
    _Float16* __restrict__ W)
{
  __shared__ _Float16 ldsQ[64 * 512];
  __shared__ float ldsB[TS * 8];
  const int tid = threadIdx.x;
  const int kt = blockIdx.x;   // 0..31
  const int ut = blockIdx.y;   // 0..15
  for (int i = tid; i < TS * 8; i += 256) ldsB[i] = Bt[i];
  const float* qb = Qw + (size_t)(kt * 64) * 8192 + ut * 512;
#pragma unroll
  for (int i = 0; i < 32; ++i) {
    int s = i * 256 + tid;
    int dk = s >> 7, c4 = s & 127;
    float4 v = *(const float4*)(qb + (size_t)dk * 8192 + c4 * 4);
    _Float16* d = &ldsQ[dk * 512 + c4 * 4];
    d[0] = (_Float16)v.x; d[1] = (_Float16)v.y;
    d[2] = (_Float16)v.z; d[3] = (_Float16)v.w;
  }
  __syncthreads();
  const int w = tid >> 6, lane = tid & 63;
  const int dur = lane & 7, ko = lane >> 3;
#pragma unroll 1
  for (int sp = 0; sp < 2; ++sp) {
    const int stripe = w * 2 + sp;
    const int du = stripe * 8 + dur;
    float Q[8][8];
#pragma unroll
    for (int j = 0; j < 8; ++j)
#pragma unroll
      for (int q = 0; q < 8; ++q)
        Q[j][q] = (float)ldsQ[(ko * 8 + j) * 512 + du * 8 + q];
    const int obase = tile_off(du, ko);
#pragma unroll 1
    for (int t = 0; t < TS; ++t) {
      float b[8];
#pragma unroll
      for (int q = 0; q < 8; ++q) b[q] = ldsB[t * 8 + q];
      half8 v;
#pragma unroll
      for (int j = 0; j < 8; ++j) {
        float s = 0.f;
#pragma unroll
        for (int q = 0; q < 8; ++q) s += Q[j][q] * b[q];
        v[j] = (_Float16)s;
      }
      size_t tile = ((size_t)t * 16 + ut) * 32 + kt;
      *(half8*)((char*)W + tile * 8192 + obase) = v;
    }
  }
}

// ---------------- xprep: x fp32 -> X tiled f16 (verified) -------------------
__global__ __launch_bounds__(256) void xprep(
    const float* __restrict__ x, _Float16* __restrict__ X)
{
  __shared__ char stage[8192];
  const int tid = threadIdx.x;
  const int bt = blockIdx.x, t = blockIdx.y;
  char* outb = (char*)X + ((size_t)(t * 32 + bt) * 16) * 8192;
  const int r = tid >> 2, cq = tid & 3;
#pragma unroll 1
  for (int kt = 0; kt < 16; ++kt) {
    const float* src =
        x + (size_t)(bt * 64 + r) * (TS * NI) + (size_t)t * NI + kt * 64 + cq * 16;
    float4 a0 = *(const float4*)(src);
    float4 a1 = *(const float4*)(src + 4);
    float4 a2 = *(const float4*)(src + 8);
    float4 a3 = *(const float4*)(src + 12);
    half8 h0, h1;
    h0[0] = (_Float16)a0.x; h0[1] = (_Float16)a0.y;
    h0[2] = (_Float16)a0.z; h0[3] = (_Float16)a0.w;
    h0[4] = (_Float16)a1.x; h0[5] = (_Float16)a1.y;
    h0[6] = (_Float16)a1.z; h0[7] = (_Float16)a1.w;
    h1[0] = (_Float16)a2.x; h1[1] = (_Float16)a2.y;
    h1[2] = (_Float16)a2.z; h1[3] = (_Float16)a2.w;
    h1[4] = (_Float16)a3.x; h1[5] = (_Float16)a3.y;
    h1[6] = (_Float16)a3.z; h1[7] = (_Float16)a3.w;
    *(half8*)(stage + tile_off(r, cq * 2)) = h0;
    *(half8*)(stage + tile_off(r, cq * 2 + 1)) = h1;
    __syncthreads();
    uint4 v0 = *(const uint4*)(stage + tid * 32);
    uint4 v1 = *(const uint4*)(stage + tid * 32 + 16);
    *(uint4*)(outb + (size_t)kt * 8192 + tid * 32) = v0;
    *(uint4*)(outb + (size_t)kt * 8192 + tid * 32 + 16) = v1;
    __syncthreads();
  }
}

// ---------------- hinit (verified) ------------------------------------------
__global__ __launch_bounds__(256) void hinit(const float* __restrict__ h0,
                                             _Float16* __restrict__ hb) {
  int g = blockIdx.x * 256 + threadIdx.x;
  int tile_id = g >> 9, rc = g & 511;
  int bt = tile_id >> 4, kt = tile_id & 15;
  int r = rc >> 3, c8 = rc & 7;
  const float* src = h0 + (size_t)(bt * 64 + r) * NU + kt * 64 + c8 * 8;
  float4 v0 = *(const float4*)src;
  float4 v1 = *(const float4*)(src + 4);
  half8 h;
  h[0] = (_Float16)v0.x; h[1] = (_Float16)v0.y;
  h[2] = (_Float16)v0.z; h[3] = (_Float16)v0.w;
  h[4] = (_Float16)v1.x; h[5] = (_Float16)v1.y;
  h[6] = (_Float16)v1.z; h[7] = (_Float16)v1.w;
  *(half8*)((char*)hb + (size_t)tile_id * 8192 + tile_off(r, c8)) = h;
}

// ---------------- xproj4: pre_frag[t] = x_t @ Wx_t + bias -------------------
// 128x128 block, 4 waves of 64x64. Both operands DMA'd (ring-2, vmcnt(8)).
// Epilogue: direct register->global stores in fragment order (no LDS).
__global__ __launch_bounds__(256) void xproj4(
    const _Float16* __restrict__ X, const _Float16* __restrict__ W,
    const float* __restrict__ bias, _Float16* __restrict__ pre)
{
  __shared__ char lds[65536];  // 2 bufs x (A 16KB | B 16KB)
  const int tid = threadIdx.x;
  const int bt2 = blockIdx.x;   // 0..15
  const int ut2 = blockIdx.y;   // 0..7
  const int t   = blockIdx.z;
  const int lane = tid & 63, w = tid >> 6;
  const int wm2 = w >> 1, wn2 = w & 1;
  const int l15 = lane & 15, lk = lane >> 4;

  const char* Xb = (const char*)X + (((size_t)t * 32 + bt2 * 2) * 16) * 8192;
  const char* Wb = (const char*)W + (((size_t)t * 16 + ut2 * 2) * 32 + 16) * 8192;

  float bv[4];
#pragma unroll
  for (int nf = 0; nf < 4; ++nf)
    bv[nf] = bias[ut2 * 128 + wn2 * 64 + nf * 16 + l15];

  auto issue = [&](int p) {
    const char* src = (w < 2)
        ? Xb + (size_t)w * (16 * 8192) + (size_t)p * 8192
        : Wb + (size_t)(w - 2) * (32 * 8192) + (size_t)p * 8192;
    src += lane * 16;
    char* dst = lds + (p & 1) * 32768 + w * 8192;
#pragma unroll
    for (int i = 0; i < 8; ++i) gload16(src + i * 1024, dst + i * 1024);
  };

  floatx4 acc[4][4] = {};

  auto comp = [&](int p) {
    const char* pA = lds + (p & 1) * 32768 + wm2 * 8192;
    const char* pB = lds + (p & 1) * 32768 + 16384 + wn2 * 8192;
    __builtin_amdgcn_s_setprio(1);
#pragma unroll
    for (int kk = 0; kk < 2; ++kk) {
      half8 af[4], bf[4];
#pragma unroll
      for (int mf = 0; mf < 4; ++mf)
        af[mf] = *(const half8*)(pA + ((mf * 2 + kk) << 10) + lane * 16);
#pragma unroll
      for (int nf = 0; nf < 4; ++nf)
        bf[nf] = *(const half8*)(pB + ((nf * 2 + kk) << 10) + lane * 16);
#pragma unroll
      for (int mf = 0; mf < 4; ++mf)
#pragma unroll
        for (int nf = 0; nf < 4; ++nf)
          acc[mf][nf] = __builtin_amdgcn_mfma_f32_16x16x32_f16(
              af[mf], bf[nf], acc[mf][nf], 0, 0, 0);
    }
    __builtin_amdgcn_s_setprio(0);
  };

  issue(0);
#pragma unroll 1
  for (int p = 0; p < 16; ++p) {
    if (p + 1 < 16) {
      issue(p + 1);
      asm volatile("s_waitcnt vmcnt(8)" ::: "memory");
    } else {
      asm volatile("s_waitcnt vmcnt(0)" ::: "memory");
    }
    __builtin_amdgcn_s_barrier();   // phase-p tiles visible to all waves
    comp(p);
    __builtin_amdgcn_s_barrier();   // comp(p) done before issue(p+2) reuses buf
  }

  // epilogue: fragment-order pre stores (register -> global, no LDS).
  // serial tile (tb,tu) = (2*bt2 + wm2_s, 2*ut2 + wn2_s); this thread's
  // acc[mf'][nf'] feeds serial wave (mf'>>1, nf'>>1), frag (mf'&1, nf'&1).
  char* pbase = (char*)pre + (size_t)t * (512 * 8192);
#pragma unroll
  for (int ws_ = 0; ws_ < 4; ++ws_) {
    int wmS = ws_ >> 1, wnS = ws_ & 1;   // serial wave coords
    _Float16 hv[16];
#pragma unroll
    for (int mfl = 0; mfl < 2; ++mfl)
#pragma unroll
      for (int nfl = 0; nfl < 2; ++nfl) {
        int mfp = wmS * 2 + mfl, nfp = wnS * 2 + nfl;
#pragma unroll
        for (int j = 0; j < 4; ++j)
          hv[((mfl * 2 + nfl) << 2) + j] = (_Float16)(acc[mfp][nfp][j] + bv[nfp]);
      }
    int bidS = (bt2 * 2 + wm2) + 32 * (ut2 * 2 + wn2);
    int tidS = ws_ * 64 + lane;
    char* dst = pbase + ((size_t)bidS * 256 + tidS) * 32;
    *(uint4*)dst = ((const uint4*)hv)[0];
    *(uint4*)(dst + 16) = ((const uint4*)hv)[1];
  }
}

// ---------------- serial4: h_t = tanh(h_{t-1} @ Wh_t + pre_t) ---------------
// R8 serial2 structure (measured fastest): ring-4 DMA, depth-3, counted vmcnt,
// raw barrier per phase, scattered-store epilogue. New: coalesced frag-order
// pre load (2 x dwordx4) + 8x8 XCD swizzle (per-XCD L2 footprint 2.5->2 MB).
__global__ __launch_bounds__(256) void serial4(
    const _Float16* __restrict__ Wh,    // W + t*UD (tiled)
    const _Float16* __restrict__ pret,  // pre_frag + t*SLOT
    const _Float16* __restrict__ hprev, // tiled
    _Float16* __restrict__ hnext,       // tiled
    float* __restrict__ outt)           // out + t*NU, row stride TS*NU
{
  __shared__ uint4 lds4[4096];          // 64 KB: 4 bufs x (A 8KB | B 8KB)
  const int tid = threadIdx.x, bid = blockIdx.x;
  // 8x8 XCD swizzle: xcd = bid&7 hosts 8 bt-panels x 8 ut-panels (bijective)
  const int xcd = bid & 7, kblk = bid >> 3;
  const int bt = (xcd & 3) * 8 + (kblk & 7);
  const int ut = (xcd >> 2) * 8 + (kblk >> 3);
  const int bidS = bt + 32 * ut;        // tile identity (matches xproj4)
  const int lane = tid & 63, w = tid >> 6;
  const int wm = w >> 1, wn = w & 1;
  const int l15 = lane & 15, lk = lane >> 4;
  const int b0 = bt * 64, u0 = ut * 64;

  // coalesced frag-order pre prefetch (oldest vmcnt entries; 2 instructions)
  uint4 prv0, prv1;
  {
    const uint4* pp = (const uint4*)((const char*)pret +
                                     ((size_t)bidS * 256 + tid) * 32);
    prv0 = pp[0];
    prv1 = pp[1];
  }

  const char* Hb = (const char*)hprev + (size_t)bt * 16 * 8192;
  const char* Wb = (const char*)Wh + (size_t)ut * 32 * 8192;

  auto issue = [&](int kt) {
    char* la = (char*)lds4 + (kt & 3) * 16384 + w * 2048;
    const char* ga = Hb + (size_t)kt * 8192 + w * 2048 + lane * 16;
    const char* gb = Wb + (size_t)kt * 8192 + w * 2048 + lane * 16;
    gload16(ga, la);
    gload16(ga + 1024, la + 1024);
    gload16(gb, la + 8192);
    gload16(gb + 1024, la + 8192 + 1024);
  };

  floatx4 acc[2][2] = {};

  issue(0);
  issue(1);
  issue(2);
#pragma unroll 1
  for (int p = 0; p < 16; ++p) {
    if (p < 14)       asm volatile("s_waitcnt vmcnt(8)" ::: "memory");
    else if (p == 14) asm volatile("s_waitcnt vmcnt(4)" ::: "memory");
    else              asm volatile("s_waitcnt vmcnt(0)" ::: "memory");
    __builtin_amdgcn_s_barrier();      // all waves' phase-p data in LDS
    if (p + 3 < 16) issue(p + 3);      // buf (p-1)&3 free
    const char* pA = (const char*)lds4 + (p & 3) * 16384;
    const char* pB = pA + 8192;
    __builtin_amdgcn_s_setprio(1);
#pragma unroll
    for (int kk = 0; kk < 2; ++kk) {
      half8 af[2], bf[2];
#pragma unroll
      for (int mf = 0; mf < 2; ++mf)
        af[mf] = *(const half8*)(pA + ((((wm * 2 + mf) * 2 + kk) << 10) + lane * 16));
#pragma unroll
      for (int nf = 0; nf < 2; ++nf)
        bf[nf] = *(const half8*)(pB + ((((wn * 2 + nf) * 2 + kk) << 10) + lane * 16));
#pragma unroll
      for (int mf = 0; mf < 2; ++mf)
#pragma unroll
        for (int nf = 0; nf < 2; ++nf)
          acc[mf][nf] = __builtin_amdgcn_mfma_f32_16x16x32_f16(
              af[mf], bf[nf], acc[mf][nf], 0, 0, 0);
    }
    __builtin_amdgcn_s_setprio(0);
  }

  const _Float16* pr = (const _Float16*)&prv0;  // prv0,prv1 contiguous 16 halves
  _Float16 prh[16];
  *(uint4*)&prh[0] = prv0;
  *(uint4*)&prh[8] = prv1;
#pragma unroll
  for (int mf = 0; mf < 2; ++mf)
#pragma unroll
    for (int nf = 0; nf < 2; ++nf) {
      int u = u0 + wn * 32 + nf * 16 + l15;
      int brow = b0 + wm * 32 + mf * 16 + (lk << 2);
#pragma unroll
      for (int j = 0; j < 4; ++j) {
        int b = brow + j;
        float p = (float)prh[((mf * 2 + nf) << 2) + j];
        float v = tanh_fast(acc[mf][nf][j] + p);
        outt[(size_t)b * (TS * NU) + u] = v;
        *(_Float16*)((char*)hnext + (((size_t)(bt * 16 + ut)) << 13) +
                     tile_off(b & 63, (u & 63) >> 3) + (u & 7) * 2) = (_Float16)v;
      }
    }
  (void)pr;
}

// ================= round-1 fallback path (small ws) =========================
__global__ __launch_bounds__(256) void wprep_lin(
    const float* __restrict__ Qw, const float* __restrict__ Bt,
    _Float16* __restrict__ W, int t0, int nt)
{
  __shared__ float ldsQ[32 * 257];
  __shared__ float ldsB[TS * 8];
  const int tid = threadIdx.x;
  const int k0 = blockIdx.x * 32;
  const int u0 = blockIdx.y * 32;
  for (int i = tid; i < TS * 8; i += 256) ldsB[i] = Bt[i];
  const float* qbase = Qw + (size_t)k0 * 8192 + (size_t)u0 * 8;
#pragma unroll
  for (int i = 0; i < 8; ++i) {
    int s = i * 256 + tid;
    int r = s >> 6, c4 = s & 63;
    float4 v = *(const float4*)(qbase + (size_t)r * 8192 + c4 * 4);
    float* d = &ldsQ[r * 257 + c4 * 4];
    d[0] = v.x; d[1] = v.y; d[2] = v.z; d[3] = v.w;
  }
  __syncthreads();
  const int kl = tid & 31;
  const int ug = tid >> 5;
#pragma unroll
  for (int p = 0; p < 4; ++p) {
    int uu = p * 8 + ug;
    float q[8];
#pragma unroll
    for (int j = 0; j < 8; ++j) q[j] = ldsQ[kl * 257 + uu * 8 + j];
    size_t obase = (size_t)(u0 + uu) * 2048 + k0 + kl;
    for (int tt = 0; tt < nt; ++tt) {
      const float* bt = &ldsB[(t0 + tt) * 8];
      float v = 0.f;
#pragma unroll
      for (int j = 0; j < 8; ++j) v += q[j] * bt[j];
      W[(size_t)tt * UD + obase] = (_Float16)v;
    }
  }
}

__global__ __launch_bounds__(256) void step_gemm(
    const float* __restrict__ xt, const float* __restrict__ hp, long hstride,
    const _Float16* __restrict__ Wt, const float* __restrict__ bias,
    float* __restrict__ outt)
{
  __shared__ _Float16 ldsA[2][64 * 64];
  __shared__ _Float16 ldsB[2][128 * 64];
  const int tid = threadIdx.x;
  const int b0 = blockIdx.x * 64;
  const int u0 = blockIdx.y * 128;
  const int lane = tid & 63;
  const int wv = tid >> 6;
  const int wm = wv >> 1, wn = wv & 1;
  const int l15 = lane & 15, lk = lane >> 4;

  float4 areg[4];
  uint4 breg[4];

  auto stage_load = [&](int kt) {
    const int k0 = kt * 64;
    const float* src; size_t stride; int koff;
    if (k0 < NU) { src = hp; stride = (size_t)hstride; koff = k0; }
    else { src = xt; stride = (size_t)TS * NI; koff = k0 - NU; }
#pragma unroll
    for (int i = 0; i < 4; ++i) {
      int s = i * 256 + tid;
      int r = s >> 4, c4 = s & 15;
      areg[i] = *(const float4*)(src + (size_t)(b0 + r) * stride + koff + c4 * 4);
    }
    const _Float16* wsrc = Wt + (size_t)u0 * 2048 + k0;
#pragma unroll
    for (int i = 0; i < 4; ++i) {
      int s = i * 256 + tid;
      int u = s >> 3, c8 = s & 7;
      breg[i] = *(const uint4*)(wsrc + (size_t)u * 2048 + c8 * 8);
    }
  };

  auto stage_write = [&](int buf) {
    char* pA = (char*)&ldsA[buf][0];
    char* pB = (char*)&ldsB[buf][0];
#pragma unroll
    for (int i = 0; i < 4; ++i) {
      int s = i * 256 + tid;
      int r = s >> 4, c4 = s & 15;
      half4v h;
      h[0] = (_Float16)areg[i].x; h[1] = (_Float16)areg[i].y;
      h[2] = (_Float16)areg[i].z; h[3] = (_Float16)areg[i].w;
      int off = (r * 128 + c4 * 8) ^ ((r & 7) << 4);
      *(half4v*)(pA + off) = h;
    }
#pragma unroll
    for (int i = 0; i < 4; ++i) {
      int s = i * 256 + tid;
      int u = s >> 3, c8 = s & 7;
      int off = (u * 128 + c8 * 16) ^ ((u & 7) << 4);
      *(uint4*)(pB + off) = breg[i];
    }
  };

  floatx4 acc[2][4] = {};

  auto compute = [&](int buf) {
    const char* pA = (const char*)&ldsA[buf][0];
    const char* pB = (const char*)&ldsB[buf][0];
#pragma unroll
    for (int kk = 0; kk < 2; ++kk) {
      half8 af[2], bf[4];
#pragma unroll
      for (int mf = 0; mf < 2; ++mf) {
        int r = wm * 32 + mf * 16 + l15;
        int off = r * 128 + ((((kk << 2) | lk) ^ (r & 7)) << 4);
        af[mf] = *(const half8*)(pA + off);
      }
#pragma unroll
      for (int nf = 0; nf < 4; ++nf) {
        int u = wn * 64 + nf * 16 + l15;
        int off = u * 128 + ((((kk << 2) | lk) ^ (u & 7)) << 4);
        bf[nf] = *(const half8*)(pB + off);
      }
#pragma unroll
      for (int mf = 0; mf < 2; ++mf)
#pragma unroll
        for (int nf = 0; nf < 4; ++nf)
          acc[mf][nf] =
              __builtin_amdgcn_mfma_f32_16x16x32_f16(af[mf], bf[nf], acc[mf][nf], 0, 0, 0);
    }
  };

  stage_load(0);
  stage_write(0);
  __syncthreads();
#pragma unroll 1
  for (int kt = 0; kt < 32; ++kt) {
    int cur = kt & 1;
    if (kt + 1 < 32) stage_load(kt + 1);
    compute(cur);
    if (kt + 1 < 32) stage_write(cur ^ 1);
    __syncthreads();
  }

#pragma unroll
  for (int mf = 0; mf < 2; ++mf)
#pragma unroll
    for (int nf = 0; nf < 4; ++nf) {
      int u = u0 + wn * 64 + nf * 16 + l15;
      float bv = bias[u];
      int brow = b0 + wm * 32 + mf * 16 + (lk << 2);
#pragma unroll
      for (int j = 0; j < 4; ++j) {
        float prev = acc[mf][nf][j] + bv;
        outt[(size_t)(brow + j) * (TS * NU) + u] = tanh_fast(prev);
      }
    }
}

extern "C" void kernel_launch(void* const* d_in, const int* in_sizes, int n_in,
                              void* d_out, int out_size, void* d_ws, size_t ws_size,
                              hipStream_t stream) {
  const float* x    = (const float*)d_in[0];
  const float* h0   = (const float*)d_in[1];
  const float* Qw   = (const float*)d_in[2];
  const float* bias = (const float*)d_in[3];
  const float* Bt   = (const float*)d_in[4];
  float* out = (float*)d_out;

  char* ws = (char*)d_ws;
  const size_t w_bytes    = (size_t)UD * TS * sizeof(_Float16);      // 167.8 MB
  const size_t x_bytes    = w_bytes;                                 // 167.8 MB
  const size_t pre_bytes  = w_bytes;                                 // 167.8 MB
  const size_t slot_bytes = (size_t)NB * NU * sizeof(_Float16);      // 4 MB
  const size_t need = w_bytes + x_bytes + pre_bytes + 2 * slot_bytes;

  if (ws_size >= need) {
    _Float16* W   = (_Float16*)ws;
    _Float16* X   = (_Float16*)(ws + w_bytes);
    _Float16* pre = (_Float16*)(ws + w_bytes + x_bytes);
    _Float16* hb  = (_Float16*)(ws + w_bytes + x_bytes + pre_bytes);
    const size_t SLOT = (size_t)NB * NU;  // elems (4 MB)

    wprep<<<dim3(32, 16), 256, 0, stream>>>(Qw, Bt, W);
    xprep<<<dim3(32, 40), 256, 0, stream>>>(x, X);
    hinit<<<dim3(1024), 256, 0, stream>>>(h0, hb);  // slot 0
    xproj4<<<dim3(16, 8, TS), 256, 0, stream>>>(X, W, bias, pre);

    for (int t = 0; t < TS; ++t) {
      const _Float16* hprev = hb + (size_t)(t & 1) * SLOT;
      _Float16* hnext = hb + (size_t)((t + 1) & 1) * SLOT;
      serial4<<<dim3(512), 256, 0, stream>>>(
          W + (size_t)t * UD, pre + (size_t)t * SLOT, hprev, hnext,
          out + (size_t)t * NU);
    }
  } else {
    // round-1 fallback (linear W layout)
    _Float16* W = (_Float16*)ws;
    const bool big = ws_size >= w_bytes;
    if (big) wprep_lin<<<dim3(64, 32), 256, 0, stream>>>(Qw, Bt, W, 0, TS);
    for (int t = 0; t < TS; ++t) {
      const _Float16* Wtp;
      if (big) {
        Wtp = W + (size_t)t * UD;
      } else {
        wprep_lin<<<dim3(64, 32), 256, 0, stream>>>(Qw, Bt, W, t, 1);
        Wtp = W;
      }
      const float* hp = (t == 0) ? h0 : out + (size_t)(t - 1) * NU;
      long hstride = (t == 0) ? NU : (long)TS * NU;
      step_gemm<<<dim3(32, 8), 256, 0, stream>>>(
          x + (size_t)t * NI, hp, hstride, Wtp, bias, out + (size_t)t * NU);
    }
  }
}

// Round 14
// 940.166 us; speedup vs baseline: 1.2163x; 1.0306x over previous
//
#include <hip/hip_runtime.h>
#include <hip/hip_fp16.h>

#define TS 40
#define NB 2048
#define NU 1024
#define NI 1024
#define ND 2048
#define UD (1024 * 2048)  // elems in one W_t (4 MB as f16)

typedef _Float16 half8 __attribute__((ext_vector_type(8)));
typedef _Float16 half4v __attribute__((ext_vector_type(4)));
typedef float floatx4 __attribute__((ext_vector_type(4)));

__device__ __forceinline__ float tanh_fast(float v) {
  float e = __expf(2.0f * v);
  return 1.0f - 2.0f / (e + 1.0f);  // inf-safe
}

__device__ __forceinline__ void gload16(const void* g, void* l) {
  __builtin_amdgcn_global_load_lds(
      (const __attribute__((address_space(1))) void*)g,
      (__attribute__((address_space(3))) void*)l, 16, 0, 0);
}

// ===== fragment-major tile layout (verified R6-R12) =========================
// tile = 64x64 f16 = 8192 B as 512 x 16B chunks.
// chunk(r,c8) = ((r>>4)*2 + (c8>>2))*64 + (c8&3)*16 + (r&15)
__device__ __forceinline__ int tile_off(int r, int c8) {
  return (((((r >> 4) * 2 + (c8 >> 2)) << 6) + ((c8 & 3) << 4) + (r & 15)) << 4);
}

// W_tiled:  [t][ut 0..15][kt 0..31][8192B]  (kt<16: h-part, kt>=16: x-part)
// X_tiled:  [t][bt 0..31][kt 0..15][8192B]
// h_tiled:  [slot][bt 0..31][ut 0..15][8192B]
// pre_frag: [t][bid_s = bt+32*ut][tid_s 0..255][16 f16]  (4 MB per t)

// ---------------- merged prep: wprep | xprep | hinit in one dispatch --------
// blocks [0,512): wprep (kt=bid&31, ut=bid>>5)
// blocks [512,1792): xprep (bt=(bid-512)&31, t=(bid-512)>>5)
// blocks [1792,2816): hinit
// LDS union: wprep needs 65536 (Q) + 1280 (B, TS*8 floats) = 66816 B.
__global__ __launch_bounds__(256) void prep_all(
    const float* __restrict__ Qw, const float* __restrict__ Bt,
    _Float16* __restrict__ W,
    const float* __restrict__ x, _Float16* __restrict__ X,
    const float* __restrict__ h0, _Float16* __restrict__ hb)
{
  __shared__ char shm[66816];  // R13 bug: was 66560 -> ldsB overflow for t>=32
  const int tid = threadIdx.x;
  const int bid = blockIdx.x;

  if (bid < 512) {
    // ---- wprep ----
    _Float16* ldsQ = (_Float16*)shm;
    float* ldsB = (float*)(shm + 65536);
    const int kt = bid & 31;
    const int ut = bid >> 5;
    for (int i = tid; i < TS * 8; i += 256) ldsB[i] = Bt[i];
    const float* qb = Qw + (size_t)(kt * 64) * 8192 + ut * 512;
#pragma unroll
    for (int i = 0; i < 32; ++i) {
      int s = i * 256 + tid;
      int dk = s >> 7, c4 = s & 127;
      float4 v = *(const float4*)(qb + (size_t)dk * 8192 + c4 * 4);
      _Float16* d = &ldsQ[dk * 512 + c4 * 4];
      d[0] = (_Float16)v.x; d[1] = (_Float16)v.y;
      d[2] = (_Float16)v.z; d[3] = (_Float16)v.w;
    }
    __syncthreads();
    const int w = tid >> 6, lane = tid & 63;
    const int dur = lane & 7, ko = lane >> 3;
#pragma unroll 1
    for (int sp = 0; sp < 2; ++sp) {
      const int stripe = w * 2 + sp;
      const int du = stripe * 8 + dur;
      float Q[8][8];
#pragma unroll
      for (int j = 0; j < 8; ++j)
#pragma unroll
        for (int q = 0; q < 8; ++q)
          Q[j][q] = (float)ldsQ[(ko * 8 + j) * 512 + du * 8 + q];
      const int obase = tile_off(du, ko);
#pragma unroll 1
      for (int t = 0; t < TS; ++t) {
        float b[8];
#pragma unroll
        for (int q = 0; q < 8; ++q) b[q] = ldsB[t * 8 + q];
        half8 v;
#pragma unroll
        for (int j = 0; j < 8; ++j) {
          float s = 0.f;
#pragma unroll
          for (int q = 0; q < 8; ++q) s += Q[j][q] * b[q];
          v[j] = (_Float16)s;
        }
        size_t tile = ((size_t)t * 16 + ut) * 32 + kt;
        *(half8*)((char*)W + tile * 8192 + obase) = v;
      }
    }
  } else if (bid < 1792) {
    // ---- xprep ----
    char* stage = shm;
    const int b2 = bid - 512;
    const int bt = b2 & 31, t = b2 >> 5;
    char* outb = (char*)X + ((size_t)(t * 32 + bt) * 16) * 8192;
    const int r = tid >> 2, cq = tid & 3;
#pragma unroll 1
    for (int kt = 0; kt < 16; ++kt) {
      const float* src =
          x + (size_t)(bt * 64 + r) * (TS * NI) + (size_t)t * NI + kt * 64 + cq * 16;
      float4 a0 = *(const float4*)(src);
      float4 a1 = *(const float4*)(src + 4);
      float4 a2 = *(const float4*)(src + 8);
      float4 a3 = *(const float4*)(src + 12);
      half8 h0v, h1v;
      h0v[0] = (_Float16)a0.x; h0v[1] = (_Float16)a0.y;
      h0v[2] = (_Float16)a0.z; h0v[3] = (_Float16)a0.w;
      h0v[4] = (_Float16)a1.x; h0v[5] = (_Float16)a1.y;
      h0v[6] = (_Float16)a1.z; h0v[7] = (_Float16)a1.w;
      h1v[0] = (_Float16)a2.x; h1v[1] = (_Float16)a2.y;
      h1v[2] = (_Float16)a2.z; h1v[3] = (_Float16)a2.w;
      h1v[4] = (_Float16)a3.x; h1v[5] = (_Float16)a3.y;
      h1v[6] = (_Float16)a3.z; h1v[7] = (_Float16)a3.w;
      *(half8*)(stage + tile_off(r, cq * 2)) = h0v;
      *(half8*)(stage + tile_off(r, cq * 2 + 1)) = h1v;
      __syncthreads();
      uint4 v0 = *(const uint4*)(stage + tid * 32);
      uint4 v1 = *(const uint4*)(stage + tid * 32 + 16);
      *(uint4*)(outb + (size_t)kt * 8192 + tid * 32) = v0;
      *(uint4*)(outb + (size_t)kt * 8192 + tid * 32 + 16) = v1;
      __syncthreads();
    }
  } else {
    // ---- hinit ----
    int g = (bid - 1792) * 256 + tid;
    int tile_id = g >> 9, rc = g & 511;
    int bt = tile_id >> 4, kt = tile_id & 15;
    int r = rc >> 3, c8 = rc & 7;
    const float* src = h0 + (size_t)(bt * 64 + r) * NU + kt * 64 + c8 * 8;
    float4 v0 = *(const float4*)src;
    float4 v1 = *(const float4*)(src + 4);
    half8 h;
    h[0] = (_Float16)v0.x; h[1] = (_Float16)v0.y;
    h[2] = (_Float16)v0.z; h[3] = (_Float16)v0.w;
    h[4] = (_Float16)v1.x; h[5] = (_Float16)v1.y;
    h[6] = (_Float16)v1.z; h[7] = (_Float16)v1.w;
    *(half8*)((char*)hb + (size_t)tile_id * 8192 + tile_off(r, c8)) = h;
  }
}

// ---------------- xproj4: pre_frag[t] = x_t @ Wx_t + bias (verified R12) ----
__global__ __launch_bounds__(256) void xproj4(
    const _Float16* __restrict__ X, const _Float16* __restrict__ W,
    const float* __restrict__ bias, _Float16* __restrict__ pre)
{
  __shared__ char lds[65536];  // 2 bufs x (A 16KB | B 16KB)
  const int tid = threadIdx.x;
  const int bt2 = blockIdx.x;   // 0..15
  const int ut2 = blockIdx.y;   // 0..7
  const int t   = blockIdx.z;
  const int lane = tid & 63, w = tid >> 6;
  const int wm2 = w >> 1, wn2 = w & 1;
  const int l15 = lane & 15, lk = lane >> 4;

  const char* Xb = (const char*)X + (((size_t)t * 32 + bt2 * 2) * 16) * 8192;
  const char* Wb = (const char*)W + (((size_t)t * 16 + ut2 * 2) * 32 + 16) * 8192;

  float bv[4];
#pragma unroll
  for (int nf = 0; nf < 4; ++nf)
    bv[nf] = bias[ut2 * 128 + wn2 * 64 + nf * 16 + l15];

  auto issue = [&](int p) {
    const char* src = (w < 2)
        ? Xb + (size_t)w * (16 * 8192) + (size_t)p * 8192
        : Wb + (size_t)(w - 2) * (32 * 8192) + (size_t)p * 8192;
    src += lane * 16;
    char* dst = lds + (p & 1) * 32768 + w * 8192;
#pragma unroll
    for (int i = 0; i < 8; ++i) gload16(src + i * 1024, dst + i * 1024);
  };

  floatx4 acc[4][4] = {};

  auto comp = [&](int p) {
    const char* pA = lds + (p & 1) * 32768 + wm2 * 8192;
    const char* pB = lds + (p & 1) * 32768 + 16384 + wn2 * 8192;
    __builtin_amdgcn_s_setprio(1);
#pragma unroll
    for (int kk = 0; kk < 2; ++kk) {
      half8 af[4], bf[4];
#pragma unroll
      for (int mf = 0; mf < 4; ++mf)
        af[mf] = *(const half8*)(pA + ((mf * 2 + kk) << 10) + lane * 16);
#pragma unroll
      for (int nf = 0; nf < 4; ++nf)
        bf[nf] = *(const half8*)(pB + ((nf * 2 + kk) << 10) + lane * 16);
#pragma unroll
      for (int mf = 0; mf < 4; ++mf)
#pragma unroll
        for (int nf = 0; nf < 4; ++nf)
          acc[mf][nf] = __builtin_amdgcn_mfma_f32_16x16x32_f16(
              af[mf], bf[nf], acc[mf][nf], 0, 0, 0);
    }
    __builtin_amdgcn_s_setprio(0);
  };

  issue(0);
#pragma unroll 1
  for (int p = 0; p < 16; ++p) {
    if (p + 1 < 16) {
      issue(p + 1);
      asm volatile("s_waitcnt vmcnt(8)" ::: "memory");
    } else {
      asm volatile("s_waitcnt vmcnt(0)" ::: "memory");
    }
    __builtin_amdgcn_s_barrier();   // phase-p tiles visible to all waves
    comp(p);
    __builtin_amdgcn_s_barrier();   // comp(p) done before issue(p+2) reuses buf
  }

  // epilogue: fragment-order pre stores (register -> global, no LDS)
  char* pbase = (char*)pre + (size_t)t * (512 * 8192);
#pragma unroll
  for (int ws_ = 0; ws_ < 4; ++ws_) {
    int wmS = ws_ >> 1, wnS = ws_ & 1;
    _Float16 hv[16];
#pragma unroll
    for (int mfl = 0; mfl < 2; ++mfl)
#pragma unroll
      for (int nfl = 0; nfl < 2; ++nfl) {
        int mfp = wmS * 2 + mfl, nfp = wnS * 2 + nfl;
#pragma unroll
        for (int j = 0; j < 4; ++j)
          hv[((mfl * 2 + nfl) << 2) + j] = (_Float16)(acc[mfp][nfp][j] + bv[nfp]);
      }
    int bidS = (bt2 * 2 + wm2) + 32 * (ut2 * 2 + wn2);
    int tidS = ws_ * 64 + lane;
    char* dst = pbase + ((size_t)bidS * 256 + tidS) * 32;
    *(uint4*)dst = ((const uint4*)hv)[0];
    *(uint4*)(dst + 16) = ((const uint4*)hv)[1];
  }
}

// ---------------- serial5: h_t = tanh(h_{t-1} @ Wh_t + pre_t) ---------------
// = R8 serial2 (measured fastest, 12.5us/step) + coalesced frag-order pre.
// NO XCD swizzle (R12's 8x8 remap regressed ~2us/step).
__global__ __launch_bounds__(256) void serial5(
    const _Float16* __restrict__ Wh,    // W + t*UD (tiled)
    const _Float16* __restrict__ pret,  // pre_frag + t*SLOT
    const _Float16* __restrict__ hprev, // tiled
    _Float16* __restrict__ hnext,       // tiled
    float* __restrict__ outt)           // out + t*NU, row stride TS*NU
{
  __shared__ uint4 lds4[4096];          // 64 KB: 4 bufs x (A 8KB | B 8KB)
  const int tid = threadIdx.x, bid = blockIdx.x;
  const int bt = bid & 31, ut = bid >> 5;
  const int bidS = bt + 32 * ut;
  const int lane = tid & 63, w = tid >> 6;
  const int wm = w >> 1, wn = w & 1;
  const int l15 = lane & 15, lk = lane >> 4;
  const int b0 = bt * 64, u0 = ut * 64;

  // coalesced frag-order pre prefetch (oldest vmcnt entries)
  uint4 prv0, prv1;
  {
    const uint4* pp = (const uint4*)((const char*)pret +
                                     ((size_t)bidS * 256 + tid) * 32);
    prv0 = pp[0];
    prv1 = pp[1];
  }

  const char* Hb = (const char*)hprev + (size_t)bt * 16 * 8192;
  const char* Wb = (const char*)Wh + (size_t)ut * 32 * 8192;

  auto issue = [&](int kt) {
    char* la = (char*)lds4 + (kt & 3) * 16384 + w * 2048;
    const char* ga = Hb + (size_t)kt * 8192 + w * 2048 + lane * 16;
    const char* gb = Wb + (size_t)kt * 8192 + w * 2048 + lane * 16;
    gload16(ga, la);
    gload16(ga + 1024, la + 1024);
    gload16(gb, la + 8192);
    gload16(gb + 1024, la + 8192 + 1024);
  };

  floatx4 acc[2][2] = {};

  issue(0);
  issue(1);
  issue(2);
#pragma unroll 1
  for (int p = 0; p < 16; ++p) {
    if (p < 14)       asm volatile("s_waitcnt vmcnt(8)" ::: "memory");
    else if (p == 14) asm volatile("s_waitcnt vmcnt(4)" ::: "memory");
    else              asm volatile("s_waitcnt vmcnt(0)" ::: "memory");
    __builtin_amdgcn_s_barrier();      // all waves' phase-p data in LDS
    if (p + 3 < 16) issue(p + 3);      // buf (p-1)&3 free
    const char* pA = (const char*)lds4 + (p & 3) * 16384;
    const char* pB = pA + 8192;
    __builtin_amdgcn_s_setprio(1);
#pragma unroll
    for (int kk = 0; kk < 2; ++kk) {
      half8 af[2], bf[2];
#pragma unroll
      for (int mf = 0; mf < 2; ++mf)
        af[mf] = *(const half8*)(pA + ((((wm * 2 + mf) * 2 + kk) << 10) + lane * 16));
#pragma unroll
      for (int nf = 0; nf < 2; ++nf)
        bf[nf] = *(const half8*)(pB + ((((wn * 2 + nf) * 2 + kk) << 10) + lane * 16));
#pragma unroll
      for (int mf = 0; mf < 2; ++mf)
#pragma unroll
        for (int nf = 0; nf < 2; ++nf)
          acc[mf][nf] = __builtin_amdgcn_mfma_f32_16x16x32_f16(
              af[mf], bf[nf], acc[mf][nf], 0, 0, 0);
    }
    __builtin_amdgcn_s_setprio(0);
  }

  _Float16 prh[16];
  *(uint4*)&prh[0] = prv0;
  *(uint4*)&prh[8] = prv1;
#pragma unroll
  for (int mf = 0; mf < 2; ++mf)
#pragma unroll
    for (int nf = 0; nf < 2; ++nf) {
      int u = u0 + wn * 32 + nf * 16 + l15;
      int brow = b0 + wm * 32 + mf * 16 + (lk << 2);
#pragma unroll
      for (int j = 0; j < 4; ++j) {
        int b = brow + j;
        float p = (float)prh[((mf * 2 + nf) << 2) + j];
        float v = tanh_fast(acc[mf][nf][j] + p);
        outt[(size_t)b * (TS * NU) + u] = v;
        *(_Float16*)((char*)hnext + (((size_t)(bt * 16 + ut)) << 13) +
                     tile_off(b & 63, (u & 63) >> 3) + (u & 7) * 2) = (_Float16)v;
      }
    }
}

// ================= round-1 fallback path (small ws) =========================
__global__ __launch_bounds__(256) void wprep_lin(
    const float* __restrict__ Qw, const float* __restrict__ Bt,
    _Float16* __restrict__ W, int t0, int nt)
{
  __shared__ float ldsQ[32 * 257];
  __shared__ float ldsB[TS * 8];
  const int tid = threadIdx.x;
  const int k0 = blockIdx.x * 32;
  const int u0 = blockIdx.y * 32;
  for (int i = tid; i < TS * 8; i += 256) ldsB[i] = Bt[i];
  const float* qbase = Qw + (size_t)k0 * 8192 + (size_t)u0 * 8;
#pragma unroll
  for (int i = 0; i < 8; ++i) {
    int s = i * 256 + tid;
    int r = s >> 6, c4 = s & 63;
    float4 v = *(const float4*)(qbase + (size_t)r * 8192 + c4 * 4);
    float* d = &ldsQ[r * 257 + c4 * 4];
    d[0] = v.x; d[1] = v.y; d[2] = v.z; d[3] = v.w;
  }
  __syncthreads();
  const int kl = tid & 31;
  const int ug = tid >> 5;
#pragma unroll
  for (int p = 0; p < 4; ++p) {
    int uu = p * 8 + ug;
    float q[8];
#pragma unroll
    for (int j = 0; j < 8; ++j) q[j] = ldsQ[kl * 257 + uu * 8 + j];
    size_t obase = (size_t)(u0 + uu) * 2048 + k0 + kl;
    for (int tt = 0; tt < nt; ++tt) {
      const float* bt = &ldsB[(t0 + tt) * 8];
      float v = 0.f;
#pragma unroll
      for (int j = 0; j < 8; ++j) v += q[j] * bt[j];
      W[(size_t)tt * UD + obase] = (_Float16)v;
    }
  }
}

__global__ __launch_bounds__(256) void step_gemm(
    const float* __restrict__ xt, const float* __restrict__ hp, long hstride,
    const _Float16* __restrict__ Wt, const float* __restrict__ bias,
    float* __restrict__ outt)
{
  __shared__ _Float16 ldsA[2][64 * 64];
  __shared__ _Float16 ldsB[2][128 * 64];
  const int tid = threadIdx.x;
  const int b0 = blockIdx.x * 64;
  const int u0 = blockIdx.y * 128;
  const int lane = tid & 63;
  const int wv = tid >> 6;
  const int wm = wv >> 1, wn = wv & 1;
  const int l15 = lane & 15, lk = lane >> 4;

  float4 areg[4];
  uint4 breg[4];

  auto stage_load = [&](int kt) {
    const int k0 = kt * 64;
    const float* src; size_t stride; int koff;
    if (k0 < NU) { src = hp; stride = (size_t)hstride; koff = k0; }
    else { src = xt; stride = (size_t)TS * NI; koff = k0 - NU; }
#pragma unroll
    for (int i = 0; i < 4; ++i) {
      int s = i * 256 + tid;
      int r = s >> 4, c4 = s & 15;
      areg[i] = *(const float4*)(src + (size_t)(b0 + r) * stride + koff + c4 * 4);
    }
    const _Float16* wsrc = Wt + (size_t)u0 * 2048 + k0;
#pragma unroll
    for (int i = 0; i < 4; ++i) {
      int s = i * 256 + tid;
      int u = s >> 3, c8 = s & 7;
      breg[i] = *(const uint4*)(wsrc + (size_t)u * 2048 + c8 * 8);
    }
  };

  auto stage_write = [&](int buf) {
    char* pA = (char*)&ldsA[buf][0];
    char* pB = (char*)&ldsB[buf][0];
#pragma unroll
    for (int i = 0; i < 4; ++i) {
      int s = i * 256 + tid;
      int r = s >> 4, c4 = s & 15;
      half4v h;
      h[0] = (_Float16)areg[i].x; h[1] = (_Float16)areg[i].y;
      h[2] = (_Float16)areg[i].z; h[3] = (_Float16)areg[i].w;
      int off = (r * 128 + c4 * 8) ^ ((r & 7) << 4);
      *(half4v*)(pA + off) = h;
    }
#pragma unroll
    for (int i = 0; i < 4; ++i) {
      int s = i * 256 + tid;
      int u = s >> 3, c8 = s & 7;
      int off = (u * 128 + c8 * 16) ^ ((u & 7) << 4);
      *(uint4*)(pB + off) = breg[i];
    }
  };

  floatx4 acc[2][4] = {};

  auto compute = [&](int buf) {
    const char* pA = (const char*)&ldsA[buf][0];
    const char* pB = (const char*)&ldsB[buf][0];
#pragma unroll
    for (int kk = 0; kk < 2; ++kk) {
      half8 af[2], bf[4];
#pragma unroll
      for (int mf = 0; mf < 2; ++mf) {
        int r = wm * 32 + mf * 16 + l15;
        int off = r * 128 + ((((kk << 2) | lk) ^ (r & 7)) << 4);
        af[mf] = *(const half8*)(pA + off);
      }
#pragma unroll
      for (int nf = 0; nf < 4; ++nf) {
        int u = wn * 64 + nf * 16 + l15;
        int off = u * 128 + ((((kk << 2) | lk) ^ (u & 7)) << 4);
        bf[nf] = *(const half8*)(pB + off);
      }
#pragma unroll
      for (int mf = 0; mf < 2; ++mf)
#pragma unroll
        for (int nf = 0; nf < 4; ++nf)
          acc[mf][nf] =
              __builtin_amdgcn_mfma_f32_16x16x32_f16(af[mf], bf[nf], acc[mf][nf], 0, 0, 0);
    }
  };

  stage_load(0);
  stage_write(0);
  __syncthreads();
#pragma unroll 1
  for (int kt = 0; kt < 32; ++kt) {
    int cur = kt & 1;
    if (kt + 1 < 32) stage_load(kt + 1);
    compute(cur);
    if (kt + 1 < 32) stage_write(cur ^ 1);
    __syncthreads();
  }

#pragma unroll
  for (int mf = 0; mf < 2; ++mf)
#pragma unroll
    for (int nf = 0; nf < 4; ++nf) {
      int u = u0 + wn * 64 + nf * 16 + l15;
      float bv = bias[u];
      int brow = b0 + wm * 32 + mf * 16 + (lk << 2);
#pragma unroll
      for (int j = 0; j < 4; ++j) {
        float prev = acc[mf][nf][j] + bv;
        outt[(size_t)(brow + j) * (TS * NU) + u] = tanh_fast(prev);
      }
    }
}

extern "C" void kernel_launch(void* const* d_in, const int* in_sizes, int n_in,
                              void* d_out, int out_size, void* d_ws, size_t ws_size,
                              hipStream_t stream) {
  const float* x    = (const float*)d_in[0];
  const float* h0   = (const float*)d_in[1];
  const float* Qw   = (const float*)d_in[2];
  const float* bias = (const float*)d_in[3];
  const float* Bt   = (const float*)d_in[4];
  float* out = (float*)d_out;

  char* ws = (char*)d_ws;
  const size_t w_bytes    = (size_t)UD * TS * sizeof(_Float16);      // 167.8 MB
  const size_t x_bytes    = w_bytes;                                 // 167.8 MB
  const size_t pre_bytes  = w_bytes;                                 // 167.8 MB
  const size_t slot_bytes = (size_t)NB * NU * sizeof(_Float16);      // 4 MB
  const size_t need = w_bytes + x_bytes + pre_bytes + 2 * slot_bytes;

  if (ws_size >= need) {
    _Float16* W   = (_Float16*)ws;
    _Float16* X   = (_Float16*)(ws + w_bytes);
    _Float16* pre = (_Float16*)(ws + w_bytes + x_bytes);
    _Float16* hb  = (_Float16*)(ws + w_bytes + x_bytes + pre_bytes);
    const size_t SLOT = (size_t)NB * NU;  // elems (4 MB)

    prep_all<<<dim3(2816), 256, 0, stream>>>(Qw, Bt, W, x, X, h0, hb);
    xproj4<<<dim3(16, 8, TS), 256, 0, stream>>>(X, W, bias, pre);

    for (int t = 0; t < TS; ++t) {
      const _Float16* hprev = hb + (size_t)(t & 1) * SLOT;
      _Float16* hnext = hb + (size_t)((t + 1) & 1) * SLOT;
      serial5<<<dim3(512), 256, 0, stream>>>(
          W + (size_t)t * UD, pre + (size_t)t * SLOT, hprev, hnext,
          out + (size_t)t * NU);
    }
  } else {
    // round-1 fallback (linear W layout)
    _Float16* W = (_Float16*)ws;
    const bool big = ws_size >= w_bytes;
    if (big) wprep_lin<<<dim3(64, 32), 256, 0, stream>>>(Qw, Bt, W, 0, TS);
    for (int t = 0; t < TS; ++t) {
      const _Float16* Wtp;
      if (big) {
        Wtp = W + (size_t)t * UD;
      } else {
        wprep_lin<<<dim3(64, 32), 256, 0, stream>>>(Qw, Bt, W, t, 1);
        Wtp = W;
      }
      const float* hp = (t == 0) ? h0 : out + (size_t)(t - 1) * NU;
      long hstride = (t == 0) ? NU : (long)TS * NU;
      step_gemm<<<dim3(32, 8), 256, 0, stream>>>(
          x + (size_t)t * NI, hp, hstride, Wtp, bias, out + (size_t)t * NU);
    }
  }
}